// Round 3
// baseline (570.915 us; speedup 1.0000x reference)
//
#include <hip/hip_runtime.h>

#define H_IN 6144
#define W_IN 6144
#define KH 7
#define KW 7
#define H_OUT (H_IN - KH + 1)   // 6138
#define W_OUT (W_IN - KW + 1)   // 6138

#define TX 64                    // output tile width
#define TY 32                    // output tile height
#define RY 8                     // output rows per thread
#define IN_W (TX + KW - 1)       // 70
#define IN_H (TY + KH - 1)       // 38
#define LDS_W 72                 // padded row stride (floats)

#define GX 96                    // grid x  = 6138/64 ceil
#define GY 192                   // grid y  = 6138/32 ceil
#define NWG (GX * GY)            // 18432, divisible by 8
#define NXCD 8

__global__ __launch_bounds__(256, 4) void conv7x7_kernel(
    const float* __restrict__ x,
    const float* __restrict__ wgt,
    const float* __restrict__ bias,
    float* __restrict__ out)
{
    __shared__ float s[IN_H][LDS_W];   // 38*72*4 = 10944 B
    __shared__ float sw[KH * KW];

    const int tid = threadIdx.x;
    const int tx  = tid & 63;          // 0..63  (x within tile)
    const int tq  = tid >> 6;          // 0..3   (wave id = y-quadrant)

    // ---- XCD-chunked bijective swizzle (NWG % 8 == 0) ----
    const int bid = blockIdx.x;
    const int swz = (bid & (NXCD - 1)) * (NWG / NXCD) + (bid >> 3);
    const int bx  = swz % GX;
    const int by  = swz / GX;

    const int x0 = bx * TX;
    const int y0 = by * TY;

    if (tid < KH * KW) sw[tid] = wgt[tid];

    // ---- stage input halo tile (coalesced, 64-wide rows + 6-col tail) ----
    for (int r = tq; r < IN_H; r += 4) {
        const int gy = y0 + r;
        const int gx = x0 + tx;
        float v = 0.f;
        if (gy < H_IN && gx < W_IN) v = x[gy * W_IN + gx];
        s[r][tx] = v;
        if (tx < IN_W - 64) {              // 6 tail columns
            const int gx2 = gx + 64;
            float v2 = 0.f;
            if (gy < H_IN && gx2 < W_IN) v2 = x[gy * W_IN + gx2];
            s[r][tx + 64] = v2;
        }
    }
    __syncthreads();

    // ---- compute: 8 output rows per thread, sliding vertical window ----
    float acc[RY];
#pragma unroll
    for (int r = 0; r < RY; ++r) acc[r] = 0.f;

    const int ry0 = tq * RY;

#pragma unroll
    for (int kx = 0; kx < KW; ++kx) {
        float v[RY + KH - 1];              // 14-row vertical window
#pragma unroll
        for (int j = 0; j < RY + KH - 1; ++j)
            v[j] = s[ry0 + j][tx + kx];
#pragma unroll
        for (int ky = 0; ky < KH; ++ky) {
            const float wv = sw[ky * KW + kx];
#pragma unroll
            for (int r = 0; r < RY; ++r)
                acc[r] = fmaf(wv, v[r + ky], acc[r]);
        }
    }

    // ---- epilogue: bias + coalesced non-temporal stores ----
    const float b  = bias[0];
    const int  ox = x0 + tx;
    if (ox < W_OUT) {
#pragma unroll
        for (int r = 0; r < RY; ++r) {
            const int oy = y0 + ry0 + r;
            if (oy < H_OUT)
                __builtin_nontemporal_store(acc[r] + b, &out[oy * W_OUT + ox]);
        }
    }
}

extern "C" void kernel_launch(void* const* d_in, const int* in_sizes, int n_in,
                              void* d_out, int out_size, void* d_ws, size_t ws_size,
                              hipStream_t stream) {
    const float* x    = (const float*)d_in[0];
    const float* wgt  = (const float*)d_in[1];
    const float* bias = (const float*)d_in[2];
    float* out        = (float*)d_out;

    conv7x7_kernel<<<dim3(NWG), dim3(256), 0, stream>>>(x, wgt, bias, out);
}

// Round 4
// 458.139 us; speedup vs baseline: 1.2462x; 1.2462x over previous
//
#include <hip/hip_runtime.h>

#define H_IN 6144
#define W_IN 6144
#define KH 7
#define KW 7
#define H_OUT (H_IN - KH + 1)   // 6138
#define W_OUT (W_IN - KW + 1)   // 6138

#define TX 64                    // output tile width
#define TY 32                    // output tile height
#define RY 8                     // output rows per thread
#define IN_W (TX + KW - 1)       // 70
#define IN_H (TY + KH - 1)       // 38
#define LDS_W 72                 // row stride (floats); 18 float4 per row
#define NV4 18                   // float4 chunks per staged row

#define GX 96                    // grid x  = 6138/64 ceil
#define GY 192                   // grid y  = 6138/32 ceil
#define NWG (GX * GY)            // 18432, divisible by 8
#define NXCD 8

__global__ __launch_bounds__(256, 4) void conv7x7_kernel(
    const float* __restrict__ x,
    const float* __restrict__ wgt,
    const float* __restrict__ bias,
    float* __restrict__ out)
{
    __shared__ float s[IN_H][LDS_W];   // 38*72*4 = 10944 B
    __shared__ float sw[KH * KW];

    const int tid = threadIdx.x;
    const int tx  = tid & 63;          // 0..63  (x within tile)
    const int tq  = tid >> 6;          // 0..3   (wave id = y-quadrant)

    // ---- XCD-chunked bijective swizzle (NWG % 8 == 0) ----
    const int bid = blockIdx.x;
    const int swz = (bid & (NXCD - 1)) * (NWG / NXCD) + (bid >> 3);
    const int bx  = swz % GX;
    const int by  = swz / GX;

    const int x0 = bx * TX;
    const int y0 = by * TY;

    if (tid < KH * KW) sw[tid] = wgt[tid];

    // ---- stage input halo tile: float4 loads (1 KB/wave/instr) ----
    // 38 rows x 18 float4 = 684 chunks; 256 threads -> ~2.7 each.
    for (int idx = tid; idx < IN_H * NV4; idx += 256) {
        const int r  = idx / NV4;
        const int c  = idx - r * NV4;
        const int gy = y0 + r;
        const int gx = x0 + (c << 2);
        float4 v = make_float4(0.f, 0.f, 0.f, 0.f);
        if (gy < H_IN) {
            if (gx + 3 < W_IN) {           // aligned: row base %16==0, gx%4==0
                v = *reinterpret_cast<const float4*>(&x[gy * W_IN + gx]);
            } else {                        // right-edge blocks only
                float t0 = (gx + 0 < W_IN) ? x[gy * W_IN + gx + 0] : 0.f;
                float t1 = (gx + 1 < W_IN) ? x[gy * W_IN + gx + 1] : 0.f;
                float t2 = (gx + 2 < W_IN) ? x[gy * W_IN + gx + 2] : 0.f;
                float t3 = (gx + 3 < W_IN) ? x[gy * W_IN + gx + 3] : 0.f;
                v = make_float4(t0, t1, t2, t3);
            }
        }
        *reinterpret_cast<float4*>(&s[r][c << 2]) = v;
    }
    __syncthreads();

    // ---- compute: 8 output rows per thread, sliding vertical window ----
    float acc[RY];
#pragma unroll
    for (int r = 0; r < RY; ++r) acc[r] = 0.f;

    const int ry0 = tq * RY;

#pragma unroll
    for (int kx = 0; kx < KW; ++kx) {
        float v[RY + KH - 1];              // 14-row vertical window
#pragma unroll
        for (int j = 0; j < RY + KH - 1; ++j)
            v[j] = s[ry0 + j][tx + kx];
#pragma unroll
        for (int ky = 0; ky < KH; ++ky) {
            const float wv = sw[ky * KW + kx];
#pragma unroll
            for (int r = 0; r < RY; ++r)
                acc[r] = fmaf(wv, v[r + ky], acc[r]);
        }
    }

    // ---- epilogue: bias + coalesced REGULAR stores (L2 write-combines) ----
    const float b  = bias[0];
    const int  ox = x0 + tx;
    if (ox < W_OUT) {
#pragma unroll
        for (int r = 0; r < RY; ++r) {
            const int oy = y0 + ry0 + r;
            if (oy < H_OUT) out[oy * W_OUT + ox] = acc[r] + b;
        }
    }
}

extern "C" void kernel_launch(void* const* d_in, const int* in_sizes, int n_in,
                              void* d_out, int out_size, void* d_ws, size_t ws_size,
                              hipStream_t stream) {
    const float* x    = (const float*)d_in[0];
    const float* wgt  = (const float*)d_in[1];
    const float* bias = (const float*)d_in[2];
    float* out        = (float*)d_out;

    conv7x7_kernel<<<dim3(NWG), dim3(256), 0, stream>>>(x, wgt, bias, out);
}